// Round 1
// baseline (339.367 us; speedup 1.0000x reference)
//
#include <hip/hip_runtime.h>

// One timestep of the AI4CFD semicircle-cylinder NS solver.
// Grid: interior NY x NX = 160 x 6600, padded PY x PX = 162 x 6602.

namespace {
constexpr int NY = 160, NX = 6600, PY = 162, PX = 6602;
constexpr int NI = NY * NX;   // 1,056,000
constexpr int NP = PY * PX;   // 1,069,524
constexpr float DT  = 0.005f;
constexpr float NU  = 0.01f;          // 1/RE
constexpr float AT  = 1.0f / 70.0f;   // 1/(RE*PR)
}

// Brinkman penalization field: semicircle at (x=1800, y=80), R=20, x>=1800.
__device__ __forceinline__ float sigma_at(int y, int x) {
    int ddx = x - 1800, ddy = y - 80;
    return ((ddx * ddx + ddy * ddy <= 400) && (x >= 1800)) ? 1.0e6f : 0.0f;
}

// ---- stencil helpers on a padded (PY x PX) array, interior coords (y,x) ----
__device__ __forceinline__ void ld9(const float* __restrict__ P, int y, int x,
                                    float r[3][3]) {
#pragma unroll
    for (int dy = 0; dy < 3; ++dy)
#pragma unroll
        for (int dx = 0; dx < 3; ++dx)
            r[dy][dx] = P[(y + dy) * PX + (x + dx)];
}
__device__ __forceinline__ float cxv(const float r[3][3]) {   // w_xadv
    return (r[0][0] - r[0][2] + 4.0f * (r[1][0] - r[1][2]) + r[2][0] - r[2][2])
           * (1.0f / 12.0f);
}
__device__ __forceinline__ float cyv(const float r[3][3]) {   // w_yadv
    return (r[0][0] + 4.0f * r[0][1] + r[0][2]
            - r[2][0] - 4.0f * r[2][1] - r[2][2]) * (1.0f / 12.0f);
}
__device__ __forceinline__ float cdv(const float r[3][3]) {   // w_diff
    return (r[0][0] + r[0][1] + r[0][2]
            + r[1][0] - 8.0f * r[1][1] + r[1][2]
            + r[2][0] + r[2][1] + r[2][2]) * (1.0f / 3.0f);
}

// ---- BC materialization: edge-pad, then override left column with value ----
__global__ void pad3_k(const float* __restrict__ a, const float* __restrict__ b,
                       const float* __restrict__ c, float va, float vb, float vc,
                       float* __restrict__ pa, float* __restrict__ pb,
                       float* __restrict__ pc) {
    int x = blockIdx.x * blockDim.x + threadIdx.x;
    int y = blockIdx.y;
    if (x >= PX) return;
    int o = y * PX + x;
    if (x == 0) { pa[o] = va; pb[o] = vb; pc[o] = vc; return; }
    int sy = min(max(y - 1, 0), NY - 1);
    int sx = min(x - 1, NX - 1);
    int s = sy * NX + sx;
    pa[o] = a[s]; pb[o] = b[s]; pc[o] = c[s];
}

__global__ void pad2_k(const float* __restrict__ a, const float* __restrict__ b,
                       float va, float vb,
                       float* __restrict__ pa, float* __restrict__ pb) {
    int x = blockIdx.x * blockDim.x + threadIdx.x;
    int y = blockIdx.y;
    if (x >= PX) return;
    int o = y * PX + x;
    if (x == 0) { pa[o] = va; pb[o] = vb; return; }
    int sy = min(max(y - 1, 0), NY - 1);
    int sx = min(x - 1, NX - 1);
    int s = sy * NX + sx;
    pa[o] = a[s]; pb[o] = b[s];
}

// bc_p: edge-pad, zero at outlet (right) column.
__global__ void padp_k(const float* __restrict__ p, float* __restrict__ pp) {
    int x = blockIdx.x * blockDim.x + threadIdx.x;
    int y = blockIdx.y;
    if (x >= PX) return;
    int o = y * PX + x;
    if (x == PX - 1) { pp[o] = 0.0f; return; }
    int sy = min(max(y - 1, 0), NY - 1);
    int sx = max(x - 1, 0);
    pp[o] = p[sy * NX + sx];
}

// Generic MacCormack half/full step:
//   out = base + dt*(ua*cx + va*cy + diff_coef*cd), then penalize / mask.
__global__ void step_k(const float* __restrict__ ubase, const float* __restrict__ vbase,
                       const float* __restrict__ Tbase,
                       const float* __restrict__ uadv, const float* __restrict__ vadv,
                       const float* __restrict__ pu, const float* __restrict__ pv,
                       const float* __restrict__ pT,
                       float dt,
                       float* __restrict__ uo, float* __restrict__ vo,
                       float* __restrict__ To) {
    int x = blockIdx.x * blockDim.x + threadIdx.x;
    int y = blockIdx.y;
    if (x >= NX) return;
    int i = y * NX + x;
    float ru[3][3], rv[3][3], rt[3][3];
    ld9(pu, y, x, ru);
    ld9(pv, y, x, rv);
    ld9(pT, y, x, rt);
    float uav = uadv[i], vav = vadv[i];
    float sig = sigma_at(y, x);
    float un = ubase[i] + dt * (uav * cxv(ru) + vav * cyv(ru) + NU * cdv(ru));
    float vn = vbase[i] + dt * (uav * cxv(rv) + vav * cyv(rv) + NU * cdv(rv));
    float Tn = Tbase[i] + dt * (uav * cxv(rt) + vav * cyv(rt) + AT * cdv(rt));
    float den = 1.0f + dt * sig;
    un /= den;
    vn /= den;
    if (sig > 0.0f) Tn = 1.0f;   // T*(1-mask)+mask
    uo[i] = un; vo[i] = vn; To[i] = Tn;
}

// Pressure Poisson RHS: (cx(uu_star) + cy(vv_star)) / DT
__global__ void rhs_k(const float* __restrict__ pu, const float* __restrict__ pv,
                      float* __restrict__ rhs) {
    int x = blockIdx.x * blockDim.x + threadIdx.x;
    int y = blockIdx.y;
    if (x >= NX) return;
    float ru[3][3], rv[3][3];
    ld9(pu, y, x, ru);
    ld9(pv, y, x, rv);
    rhs[y * NX + x] = (cxv(ru) + cyv(rv)) * (1.0f / DT);
}

// One Jacobi sweep. bc_p folded into the loads:
//   row edge-clamped; col -1 clamped to 0; col NX (outlet pad) reads 0.
__global__ void jacobi_k(const float* __restrict__ pin, const float* __restrict__ rhs,
                         float* __restrict__ pout, float* __restrict__ res) {
    int x = blockIdx.x * blockDim.x + threadIdx.x;
    int y = blockIdx.y;
    if (x >= NX) return;
    float r[3][3];
#pragma unroll
    for (int dy = 0; dy < 3; ++dy) {
        int sy = min(max(y + dy - 1, 0), NY - 1);
#pragma unroll
        for (int dx = 0; dx < 3; ++dx) {
            int sx = x + dx - 1;
            float val = 0.0f;
            if (sx < NX) val = pin[sy * NX + max(sx, 0)];
            r[dy][dx] = val;
        }
    }
    int i = y * NX + x;
    float convA = -cdv(r);              // w_A = -w_diff
    float resid = convA - rhs[i];
    pout[i] = r[1][1] - resid * 0.375f; // 1/DIAG = 3/8
    if (res) res[i] = resid;
}

// Projection: u_new = (u_star + DT*cx(pp)) / (1 + DT*sigma), same for v.
__global__ void proj_k(const float* __restrict__ us, const float* __restrict__ vs,
                       const float* __restrict__ pp,
                       float* __restrict__ un, float* __restrict__ vn) {
    int x = blockIdx.x * blockDim.x + threadIdx.x;
    int y = blockIdx.y;
    if (x >= NX) return;
    int i = y * NX + x;
    float rp[3][3];
    ld9(pp, y, x, rp);
    float sig = sigma_at(y, x);
    float den = 1.0f + DT * sig;
    un[i] = (us[i] + cxv(rp) * DT) / den;
    vn[i] = (vs[i] + cyv(rp) * DT) / den;
}

extern "C" void kernel_launch(void* const* d_in, const int* in_sizes, int n_in,
                              void* d_out, int out_size, void* d_ws, size_t ws_size,
                              hipStream_t stream) {
    const float* u = (const float*)d_in[0];
    const float* v = (const float*)d_in[1];
    const float* p = (const float*)d_in[2];
    const float* T = (const float*)d_in[3];
    // d_in[4..10] are scratch buffers (fully overwritten in the reference; no info)
    // d_in[11..14] are the fixed conv weights (hard-coded above).

    float* out = (float*)d_out;
    // Output layout: u,v,p,T (NI each), uu_star,vv_star,pp,TT,b_uu,b_vv,b_TT (NP each), residual (NI)
    float* o_u   = out;
    float* o_v   = out + (size_t)NI;
    float* o_p   = out + 2 * (size_t)NI;
    float* o_T   = out + 3 * (size_t)NI;
    float* o_uus = out + 4 * (size_t)NI;
    float* o_vvs = o_uus + (size_t)NP;
    float* o_pp  = o_uus + 2 * (size_t)NP;
    float* o_TT  = o_uus + 3 * (size_t)NP;
    float* o_buu = o_uus + 4 * (size_t)NP;
    float* o_bvv = o_uus + 5 * (size_t)NP;
    float* o_bTT = o_uus + 6 * (size_t)NP;
    float* o_res = o_uus + 7 * (size_t)NP;

    // Workspace layout (aliased across phases):
    //   slot0 NP: uu      -> u_star
    //   slot1 NP: vv      -> v_star
    //   slot2 NI: u_pred  -> jacobi ping A
    //   slot3 NI: v_pred  -> jacobi ping B
    //   slot4 NI: T_pred  -> b_rhs
    float* w    = (float*)d_ws;
    float* s_uu = w;
    float* s_vv = w + (size_t)NP;
    float* s_up = w + 2 * (size_t)NP;
    float* s_vp = s_up + (size_t)NI;
    float* s_Tp = s_up + 2 * (size_t)NI;
    float* s_us = s_uu;
    float* s_vs = s_vv;
    float* s_rhs = s_Tp;
    float* pA = s_up;
    float* pB = s_vp;

    dim3 blk(256, 1, 1);
    dim3 gi((NX + 255) / 256, NY, 1);   // interior
    dim3 gp((PX + 255) / 256, PY, 1);   // padded

    // 1. uu=bc_u(u,1.5), vv=bc_v(v,0), TT=bc_T(T)
    pad3_k<<<gp, blk, 0, stream>>>(u, v, T, 1.5f, 0.0f, 0.0f, s_uu, s_vv, o_TT);
    // 2. predictor (half step): advecting velocity = (u,v)
    step_k<<<gi, blk, 0, stream>>>(u, v, T, u, v, s_uu, s_vv, o_TT,
                                   0.5f * DT, s_up, s_vp, s_Tp);
    // 3. b_uu=bc_u(u_pred), b_vv=bc_v(v_pred), b_TT=bc_T(T_pred)
    pad3_k<<<gp, blk, 0, stream>>>(s_up, s_vp, s_Tp, 1.5f, 0.0f, 0.0f,
                                   o_buu, o_bvv, o_bTT);
    // 4. corrector (full step): advecting velocity = (u_pred,v_pred)
    step_k<<<gi, blk, 0, stream>>>(u, v, T, s_up, s_vp, o_buu, o_bvv, o_bTT,
                                   DT, s_us, s_vs, o_T);
    // 5. uu_star, vv_star
    pad2_k<<<gp, blk, 0, stream>>>(s_us, s_vs, 1.5f, 0.0f, o_uus, o_vvs);
    // 6. pressure rhs
    rhs_k<<<gi, blk, 0, stream>>>(o_uus, o_vvs, s_rhs);
    // 7. 40 Jacobi sweeps (ping-pong; last writes p and residual to d_out)
    const float* src = p;
    for (int it = 0; it < 40; ++it) {
        bool last = (it == 39);
        float* dst = last ? o_p : ((it & 1) ? pB : pA);
        jacobi_k<<<gi, blk, 0, stream>>>(src, s_rhs, dst, last ? o_res : nullptr);
        src = dst;
    }
    // 8. pp = bc_p(p)
    padp_k<<<gp, blk, 0, stream>>>(o_p, o_pp);
    // 9. projection
    proj_k<<<gi, blk, 0, stream>>>(s_us, s_vs, o_pp, o_u, o_v);
}

// Round 2
// 238.820 us; speedup vs baseline: 1.4210x; 1.4210x over previous
//
#include <hip/hip_runtime.h>

// One timestep of the AI4CFD semicircle-cylinder NS solver.
// Grid: interior NY x NX = 160 x 6600, padded PY x PX = 162 x 6602.
// Round 2: 9 launches total. Jacobi fused 8 iters/launch in LDS; pad
// (boundary-condition) outputs fused into the stencil kernels.

namespace {
constexpr int NY = 160, NX = 6600, PY = 162, PX = 6602;
constexpr int NI = NY * NX;   // 1,056,000
constexpr int NP = PY * PX;   // 1,069,524
constexpr float DT  = 0.005f;
constexpr float NU  = 0.01f;          // 1/RE
constexpr float AT  = 1.0f / 70.0f;   // 1/(RE*PR)

// fused-Jacobi geometry
constexpr int JK  = 8;                // iterations per launch (5 launches x 8 = 40)
constexpr int JW  = 24;               // strip width; NX/JW = 275 blocks
constexpr int JH  = 8;                // halo (= JK)
constexpr int JWL = JW + 2 * JH;      // 40 LDS columns
constexpr int JTX = 10;               // quad-columns per row group (10*4 = 40 >= max region)
constexpr int JTY = 32;               // row groups
constexpr int JNT = JTX * JTY;        // 320 threads
constexpr int JROWS = NY / JTY;       // 5 rows per thread
constexpr int JBLKS = NX / JW;        // 275
}

// Brinkman penalization field: semicircle at (x=1800, y=80), R=20, x>=1800.
__device__ __forceinline__ float sigma_at(int y, int x) {
    int ddx = x - 1800, ddy = y - 80;
    return ((ddx * ddx + ddy * ddy <= 400) && (x >= 1800)) ? 1.0e6f : 0.0f;
}

// ---- stencil weights ----
__device__ __forceinline__ float cxv(const float r[3][3]) {   // w_xadv
    return (r[0][0] - r[0][2] + 4.0f * (r[1][0] - r[1][2]) + r[2][0] - r[2][2])
           * (1.0f / 12.0f);
}
__device__ __forceinline__ float cyv(const float r[3][3]) {   // w_yadv
    return (r[0][0] + 4.0f * r[0][1] + r[0][2]
            - r[2][0] - 4.0f * r[2][1] - r[2][2]) * (1.0f / 12.0f);
}
__device__ __forceinline__ float cdv(const float r[3][3]) {   // w_diff
    return (r[0][0] + r[0][1] + r[0][2]
            + r[1][0] - 8.0f * r[1][1] + r[1][2]
            + r[2][0] + r[2][1] + r[2][2]) * (1.0f / 3.0f);
}

// 3x3 gather from an interior array with velocity/temperature BC semantics:
// rows edge-clamped, right edge-clamped, left column is the constant lc.
__device__ __forceinline__ void g9(const float* __restrict__ a, int y, int x,
                                   float lc, float r[3][3]) {
    int ym = max(y - 1, 0), yp = min(y + 1, NY - 1);
    int xp = min(x + 1, NX - 1);
    const float* r0 = a + (size_t)ym * NX;
    const float* r1 = a + (size_t)y  * NX;
    const float* r2 = a + (size_t)yp * NX;
    if (x == 0) { r[0][0] = lc; r[1][0] = lc; r[2][0] = lc; }
    else        { r[0][0] = r0[x-1]; r[1][0] = r1[x-1]; r[2][0] = r2[x-1]; }
    r[0][1] = r0[x]; r[0][2] = r0[xp];
    r[1][1] = r1[x]; r[1][2] = r1[xp];
    r[2][1] = r2[x]; r[2][2] = r2[xp];
}

// 3x3 gather with pressure BC: rows edge-clamped, left edge-clamped, right = 0 (outlet).
__device__ __forceinline__ void g9p(const float* __restrict__ a, int y, int x,
                                    float r[3][3]) {
    int ym = max(y - 1, 0), yp = min(y + 1, NY - 1);
    int xm = max(x - 1, 0);
    bool rb = (x == NX - 1);
    const float* r0 = a + (size_t)ym * NX;
    const float* r1 = a + (size_t)y  * NX;
    const float* r2 = a + (size_t)yp * NX;
    r[0][0] = r0[xm]; r[0][1] = r0[x]; r[0][2] = rb ? 0.0f : r0[x+1];
    r[1][0] = r1[xm]; r[1][1] = r1[x]; r[1][2] = rb ? 0.0f : r1[x+1];
    r[2][0] = r2[xm]; r[2][1] = r2[x]; r[2][2] = rb ? 0.0f : r2[x+1];
}

// K1: predictor half-step (+ writes o_TT = bc_T(T)). Padded grid.
__global__ void pred_k(const float* __restrict__ u, const float* __restrict__ v,
                       const float* __restrict__ T,
                       float* __restrict__ up, float* __restrict__ vp,
                       float* __restrict__ Tp, float* __restrict__ oTT) {
    int px = blockIdx.x * blockDim.x + threadIdx.x;
    int py = blockIdx.y;
    if (px >= PX) return;
    int y = py - 1, x = px - 1;
    int cy = min(max(y, 0), NY - 1), cx = min(max(x, 0), NX - 1);
    oTT[(size_t)py * PX + px] = (px == 0) ? 0.0f : T[(size_t)cy * NX + cx];
    if (y < 0 || y >= NY || x < 0 || x >= NX) return;
    float ru[3][3], rv[3][3], rt[3][3];
    g9(u, y, x, 1.5f, ru);
    g9(v, y, x, 0.0f, rv);
    g9(T, y, x, 0.0f, rt);
    float uav = ru[1][1], vav = rv[1][1];
    float sig = sigma_at(y, x);
    const float hdt = 0.5f * DT;
    float un = ru[1][1] + hdt * (uav * cxv(ru) + vav * cyv(ru) + NU * cdv(ru));
    float vn = rv[1][1] + hdt * (uav * cxv(rv) + vav * cyv(rv) + NU * cdv(rv));
    float Tn = rt[1][1] + hdt * (uav * cxv(rt) + vav * cyv(rt) + AT * cdv(rt));
    float den = 1.0f + hdt * sig;
    un /= den; vn /= den;
    if (sig > 0.0f) Tn = 1.0f;
    size_t i = (size_t)y * NX + x;
    up[i] = un; vp[i] = vn; Tp[i] = Tn;
}

// K2: corrector full step (+ writes b_uu/b_vv/b_TT = pads of the predictors).
__global__ void corr_k(const float* __restrict__ u, const float* __restrict__ v,
                       const float* __restrict__ T,
                       const float* __restrict__ up, const float* __restrict__ vp,
                       const float* __restrict__ Tp,
                       float* __restrict__ us, float* __restrict__ vs,
                       float* __restrict__ oT,
                       float* __restrict__ obuu, float* __restrict__ obvv,
                       float* __restrict__ obTT) {
    int px = blockIdx.x * blockDim.x + threadIdx.x;
    int py = blockIdx.y;
    if (px >= PX) return;
    int y = py - 1, x = px - 1;
    int cy = min(max(y, 0), NY - 1), cx = min(max(x, 0), NX - 1);
    size_t o = (size_t)py * PX + px, s = (size_t)cy * NX + cx;
    obuu[o] = (px == 0) ? 1.5f : up[s];
    obvv[o] = (px == 0) ? 0.0f : vp[s];
    obTT[o] = (px == 0) ? 0.0f : Tp[s];
    if (y < 0 || y >= NY || x < 0 || x >= NX) return;
    float ru[3][3], rv[3][3], rt[3][3];
    g9(up, y, x, 1.5f, ru);
    g9(vp, y, x, 0.0f, rv);
    g9(Tp, y, x, 0.0f, rt);
    float uav = ru[1][1], vav = rv[1][1];   // advecting velocity = predictor
    float sig = sigma_at(y, x);
    size_t i = (size_t)y * NX + x;
    float un = u[i] + DT * (uav * cxv(ru) + vav * cyv(ru) + NU * cdv(ru));
    float vn = v[i] + DT * (uav * cxv(rv) + vav * cyv(rv) + NU * cdv(rv));
    float Tn = T[i] + DT * (uav * cxv(rt) + vav * cyv(rt) + AT * cdv(rt));
    float den = 1.0f + DT * sig;
    un /= den; vn /= den;
    if (sig > 0.0f) Tn = 1.0f;
    us[i] = un; vs[i] = vn; oT[i] = Tn;
}

// K3: pressure Poisson rhs (+ writes uu_star/vv_star pads).
__global__ void rhsdiv_k(const float* __restrict__ us, const float* __restrict__ vs,
                         float* __restrict__ rhs,
                         float* __restrict__ ouus, float* __restrict__ ovvs) {
    int px = blockIdx.x * blockDim.x + threadIdx.x;
    int py = blockIdx.y;
    if (px >= PX) return;
    int y = py - 1, x = px - 1;
    int cy = min(max(y, 0), NY - 1), cx = min(max(x, 0), NX - 1);
    size_t o = (size_t)py * PX + px, s = (size_t)cy * NX + cx;
    ouus[o] = (px == 0) ? 1.5f : us[s];
    ovvs[o] = (px == 0) ? 0.0f : vs[s];
    if (y < 0 || y >= NY || x < 0 || x >= NX) return;
    float ru[3][3], rv[3][3];
    g9(us, y, x, 1.5f, ru);
    g9(vs, y, x, 0.0f, rv);
    rhs[(size_t)y * NX + x] = (cxv(ru) + cyv(rv)) * (1.0f / DT);
}

// K4-K8: fused Jacobi, JK iterations per launch, LDS-resident strip + halo.
__global__ __launch_bounds__(JNT)
void jacobi_fused(const float* __restrict__ pin, const float* __restrict__ rhs,
                  float* __restrict__ pout, float* __restrict__ res) {
    __shared__ float pl[2][NY][JWL];  // ping-pong pressure tiles (51.2 KB)
    __shared__ float rl[NY][JWL];     // rhs tile (25.6 KB)
    const int x0 = blockIdx.x * JW;
    const int tid = threadIdx.x;
    // cooperative load: bc_p folded (left clamp, right-of-domain = outlet 0)
    for (int i = tid; i < NY * JWL; i += JNT) {
        int y = i / JWL, lx = i - y * JWL;
        int gx = x0 - JH + lx;
        float pv = 0.0f, rv = 0.0f;
        if (gx < NX) {
            pv = pin[(size_t)y * NX + max(gx, 0)];
            if (gx >= 0) rv = rhs[(size_t)y * NX + gx];
        }
        pl[0][y][lx] = pv;
        pl[1][y][lx] = pv;   // out-of-domain right columns must be 0 in BOTH buffers
        rl[y][lx] = pv == pv ? rv : rv;  // keep simple: rl = rv
    }
    __syncthreads();
    const int tx = tid % JTX, ty = tid / JTX;
    const int y0 = ty * JROWS;
    const bool lblk = (x0 == 0), rblk = (x0 + JW == NX);
    int cb = 0;
    for (int j = 0; j < JK; ++j) {
        const int e = JK - 1 - j;
        const bool last = (e == 0);
        // valid region in LDS-x, then align to float4 quads (aligned extension
        // computes quarantined garbage that never reaches valid cells)
        int ls = lblk ? JH : (JH - e);
        int le = rblk ? (JH + JW) : (JH + JW + e);
        int ls4 = ls & ~3;
        int le4 = (le + 3) & ~3;
        int lx0 = ls4 + 4 * tx;
        if (lx0 < le4) {
            float (*cur)[JWL] = pl[cb];
            float (*nxt)[JWL] = pl[cb ^ 1];
            const int lm = max(lx0 - 2, 0);          // side read (pairs), clamped in-bounds
            const int lp = min(lx0 + 4, JWL - 2);
            const bool leftbc = lblk && (lx0 == JH); // cell0 is gx==0: left nbr = itself
            float aL, bL, cL, aR, bR, cR;
            float4 aC, bC, cC;
            auto ld = [&](int yy, float& L, float4& C, float& R) {
                const float* row = cur[yy];
                float2 a = *(const float2*)(row + lm);
                C = *(const float4*)(row + lx0);
                float2 b = *(const float2*)(row + lp);
                L = leftbc ? C.x : a.y;
                R = b.x;
            };
            ld(max(y0 - 1, 0), aL, aC, aR);
            ld(y0, bL, bC, bR);
            for (int y = y0; y < y0 + JROWS; ++y) {
                ld(min(y + 1, NY - 1), cL, cC, cR);
                float4 rq = *(const float4*)(rl[y] + lx0);
                float s0 = aL   + aC.x + aC.y + bL   + bC.y + cL   + cC.x + cC.y;
                float s1 = aC.x + aC.y + aC.z + bC.x + bC.z + cC.x + cC.y + cC.z;
                float s2 = aC.y + aC.z + aC.w + bC.y + bC.w + cC.y + cC.z + cC.w;
                float s3 = aC.z + aC.w + aR   + bC.z + bR   + cC.z + cC.w + cR;
                float r0 = (8.0f * bC.x - s0) * (1.0f / 3.0f) - rq.x;
                float r1 = (8.0f * bC.y - s1) * (1.0f / 3.0f) - rq.y;
                float r2 = (8.0f * bC.z - s2) * (1.0f / 3.0f) - rq.z;
                float r3 = (8.0f * bC.w - s3) * (1.0f / 3.0f) - rq.w;
                float4 pn = { bC.x - 0.375f * r0, bC.y - 0.375f * r1,
                              bC.z - 0.375f * r2, bC.w - 0.375f * r3 };
                if (last) {
                    int gx = x0 - JH + lx0;          // strip columns only
                    *(float4*)(pout + (size_t)y * NX + gx) = pn;
                    if (res) {
                        float4 rr = { r0, r1, r2, r3 };
                        *(float4*)(res + (size_t)y * NX + gx) = rr;
                    }
                } else {
                    *(float4*)(nxt[y] + lx0) = pn;
                }
                aL = bL; aC = bC; aR = bR;
                bL = cL; bC = cC; bR = cR;
            }
        }
        cb ^= 1;
        if (!last) __syncthreads();
    }
}

// K9: projection (+ writes o_pp = bc_p(p)).
__global__ void proj2_k(const float* __restrict__ us, const float* __restrict__ vs,
                        const float* __restrict__ p,
                        float* __restrict__ un, float* __restrict__ vn,
                        float* __restrict__ opp) {
    int px = blockIdx.x * blockDim.x + threadIdx.x;
    int py = blockIdx.y;
    if (px >= PX) return;
    int y = py - 1, x = px - 1;
    int cy = min(max(y, 0), NY - 1);
    opp[(size_t)py * PX + px] =
        (px == PX - 1) ? 0.0f : p[(size_t)cy * NX + max(x, 0)];
    if (y < 0 || y >= NY || x < 0 || x >= NX) return;
    float rp[3][3];
    g9p(p, y, x, rp);
    float sig = sigma_at(y, x);
    float den = 1.0f + DT * sig;
    size_t i = (size_t)y * NX + x;
    un[i] = (us[i] + cxv(rp) * DT) / den;
    vn[i] = (vs[i] + cyv(rp) * DT) / den;
}

extern "C" void kernel_launch(void* const* d_in, const int* in_sizes, int n_in,
                              void* d_out, int out_size, void* d_ws, size_t ws_size,
                              hipStream_t stream) {
    const float* u = (const float*)d_in[0];
    const float* v = (const float*)d_in[1];
    const float* p = (const float*)d_in[2];
    const float* T = (const float*)d_in[3];

    float* out = (float*)d_out;
    float* o_u   = out;
    float* o_v   = out + (size_t)NI;
    float* o_p   = out + 2 * (size_t)NI;
    float* o_T   = out + 3 * (size_t)NI;
    float* o_uus = out + 4 * (size_t)NI;
    float* o_vvs = o_uus + (size_t)NP;
    float* o_pp  = o_uus + 2 * (size_t)NP;
    float* o_TT  = o_uus + 3 * (size_t)NP;
    float* o_buu = o_uus + 4 * (size_t)NP;
    float* o_bvv = o_uus + 5 * (size_t)NP;
    float* o_bTT = o_uus + 6 * (size_t)NP;
    float* o_res = o_uus + 7 * (size_t)NP;

    // ws slots (5 x NI floats = 21.1 MB):
    //   w0: u_pred -> jacobi ping A    w1: v_pred -> jacobi ping B
    //   w2: T_pred -> rhs              w3: u_star  w4: v_star
    float* w  = (float*)d_ws;
    float* s_up  = w;
    float* s_vp  = w + (size_t)NI;
    float* s_Tp  = w + 2 * (size_t)NI;
    float* s_us  = w + 3 * (size_t)NI;
    float* s_vs  = w + 4 * (size_t)NI;
    float* s_rhs = s_Tp;
    float* pA = s_up;
    float* pB = s_vp;

    dim3 blk(256, 1, 1);
    dim3 gp((PX + 255) / 256, PY, 1);

    pred_k<<<gp, blk, 0, stream>>>(u, v, T, s_up, s_vp, s_Tp, o_TT);
    corr_k<<<gp, blk, 0, stream>>>(u, v, T, s_up, s_vp, s_Tp,
                                   s_us, s_vs, o_T, o_buu, o_bvv, o_bTT);
    rhsdiv_k<<<gp, blk, 0, stream>>>(s_us, s_vs, s_rhs, o_uus, o_vvs);

    // 40 Jacobi iterations = 5 fused launches x 8
    jacobi_fused<<<dim3(JBLKS), dim3(JNT), 0, stream>>>(p,  s_rhs, pA,  nullptr);
    jacobi_fused<<<dim3(JBLKS), dim3(JNT), 0, stream>>>(pA, s_rhs, pB,  nullptr);
    jacobi_fused<<<dim3(JBLKS), dim3(JNT), 0, stream>>>(pB, s_rhs, pA,  nullptr);
    jacobi_fused<<<dim3(JBLKS), dim3(JNT), 0, stream>>>(pA, s_rhs, pB,  nullptr);
    jacobi_fused<<<dim3(JBLKS), dim3(JNT), 0, stream>>>(pB, s_rhs, o_p, o_res);

    proj2_k<<<gp, blk, 0, stream>>>(s_us, s_vs, o_p, o_u, o_v, o_pp);
}

// Round 3
// 159.646 us; speedup vs baseline: 2.1258x; 1.4959x over previous
//
#include <hip/hip_runtime.h>

// One timestep of the AI4CFD semicircle-cylinder NS solver.
// Grid: interior NY x NX = 160 x 6600, padded PY x PX = 162 x 6602.
// Round 3: 2D-tiled fused Jacobi (core 32x40, halo 8, 825 blocks) for
// occupancy; aux stencil kernels unchanged. 9 launches total.

namespace {
constexpr int NY = 160, NX = 6600, PY = 162, PX = 6602;
constexpr int NI = NY * NX;   // 1,056,000
constexpr int NP = PY * PX;   // 1,069,524
constexpr float DT  = 0.005f;
constexpr float NU  = 0.01f;          // 1/RE
constexpr float AT  = 1.0f / 70.0f;   // 1/(RE*PR)

// fused-Jacobi geometry: 5 launches x JK iterations
constexpr int JK   = 8;
constexpr int HALO = 8;
constexpr int CW   = 40, CH = 32;     // core tile (per block output)
constexpr int TW   = CW + 2 * HALO;   // 56 loaded cols
constexpr int TH   = CH + 2 * HALO;   // 48 loaded rows
constexpr int TLW  = 60;              // padded LDS row stride (floats)
constexpr int BXN  = NX / CW;         // 165
constexpr int BYN  = NY / CH;         // 5
}

// Brinkman penalization field: semicircle at (x=1800, y=80), R=20, x>=1800.
__device__ __forceinline__ float sigma_at(int y, int x) {
    int ddx = x - 1800, ddy = y - 80;
    return ((ddx * ddx + ddy * ddy <= 400) && (x >= 1800)) ? 1.0e6f : 0.0f;
}

// ---- stencil weights ----
__device__ __forceinline__ float cxv(const float r[3][3]) {   // w_xadv
    return (r[0][0] - r[0][2] + 4.0f * (r[1][0] - r[1][2]) + r[2][0] - r[2][2])
           * (1.0f / 12.0f);
}
__device__ __forceinline__ float cyv(const float r[3][3]) {   // w_yadv
    return (r[0][0] + 4.0f * r[0][1] + r[0][2]
            - r[2][0] - 4.0f * r[2][1] - r[2][2]) * (1.0f / 12.0f);
}
__device__ __forceinline__ float cdv(const float r[3][3]) {   // w_diff
    return (r[0][0] + r[0][1] + r[0][2]
            + r[1][0] - 8.0f * r[1][1] + r[1][2]
            + r[2][0] + r[2][1] + r[2][2]) * (1.0f / 3.0f);
}

// 3x3 gather, velocity/temperature BC: rows edge-clamped, right edge-clamped,
// left column is constant lc.
__device__ __forceinline__ void g9(const float* __restrict__ a, int y, int x,
                                   float lc, float r[3][3]) {
    int ym = max(y - 1, 0), yp = min(y + 1, NY - 1);
    int xp = min(x + 1, NX - 1);
    const float* r0 = a + (size_t)ym * NX;
    const float* r1 = a + (size_t)y  * NX;
    const float* r2 = a + (size_t)yp * NX;
    if (x == 0) { r[0][0] = lc; r[1][0] = lc; r[2][0] = lc; }
    else        { r[0][0] = r0[x-1]; r[1][0] = r1[x-1]; r[2][0] = r2[x-1]; }
    r[0][1] = r0[x]; r[0][2] = r0[xp];
    r[1][1] = r1[x]; r[1][2] = r1[xp];
    r[2][1] = r2[x]; r[2][2] = r2[xp];
}

// 3x3 gather, pressure BC: rows edge-clamped, left edge-clamped, right = 0.
__device__ __forceinline__ void g9p(const float* __restrict__ a, int y, int x,
                                    float r[3][3]) {
    int ym = max(y - 1, 0), yp = min(y + 1, NY - 1);
    int xm = max(x - 1, 0);
    bool rb = (x == NX - 1);
    const float* r0 = a + (size_t)ym * NX;
    const float* r1 = a + (size_t)y  * NX;
    const float* r2 = a + (size_t)yp * NX;
    r[0][0] = r0[xm]; r[0][1] = r0[x]; r[0][2] = rb ? 0.0f : r0[x+1];
    r[1][0] = r1[xm]; r[1][1] = r1[x]; r[1][2] = rb ? 0.0f : r1[x+1];
    r[2][0] = r2[xm]; r[2][1] = r2[x]; r[2][2] = rb ? 0.0f : r2[x+1];
}

// K1: predictor half-step (+ writes o_TT = bc_T(T)). Padded grid.
__global__ void pred_k(const float* __restrict__ u, const float* __restrict__ v,
                       const float* __restrict__ T,
                       float* __restrict__ up, float* __restrict__ vp,
                       float* __restrict__ Tp, float* __restrict__ oTT) {
    int px = blockIdx.x * blockDim.x + threadIdx.x;
    int py = blockIdx.y;
    if (px >= PX) return;
    int y = py - 1, x = px - 1;
    int cy = min(max(y, 0), NY - 1), cx = min(max(x, 0), NX - 1);
    oTT[(size_t)py * PX + px] = (px == 0) ? 0.0f : T[(size_t)cy * NX + cx];
    if (y < 0 || y >= NY || x < 0 || x >= NX) return;
    float ru[3][3], rv[3][3], rt[3][3];
    g9(u, y, x, 1.5f, ru);
    g9(v, y, x, 0.0f, rv);
    g9(T, y, x, 0.0f, rt);
    float uav = ru[1][1], vav = rv[1][1];
    float sig = sigma_at(y, x);
    const float hdt = 0.5f * DT;
    float un = ru[1][1] + hdt * (uav * cxv(ru) + vav * cyv(ru) + NU * cdv(ru));
    float vn = rv[1][1] + hdt * (uav * cxv(rv) + vav * cyv(rv) + NU * cdv(rv));
    float Tn = rt[1][1] + hdt * (uav * cxv(rt) + vav * cyv(rt) + AT * cdv(rt));
    float den = 1.0f + hdt * sig;
    un /= den; vn /= den;
    if (sig > 0.0f) Tn = 1.0f;
    size_t i = (size_t)y * NX + x;
    up[i] = un; vp[i] = vn; Tp[i] = Tn;
}

// K2: corrector full step (+ writes b_uu/b_vv/b_TT).
__global__ void corr_k(const float* __restrict__ u, const float* __restrict__ v,
                       const float* __restrict__ T,
                       const float* __restrict__ up, const float* __restrict__ vp,
                       const float* __restrict__ Tp,
                       float* __restrict__ us, float* __restrict__ vs,
                       float* __restrict__ oT,
                       float* __restrict__ obuu, float* __restrict__ obvv,
                       float* __restrict__ obTT) {
    int px = blockIdx.x * blockDim.x + threadIdx.x;
    int py = blockIdx.y;
    if (px >= PX) return;
    int y = py - 1, x = px - 1;
    int cy = min(max(y, 0), NY - 1), cx = min(max(x, 0), NX - 1);
    size_t o = (size_t)py * PX + px, s = (size_t)cy * NX + cx;
    obuu[o] = (px == 0) ? 1.5f : up[s];
    obvv[o] = (px == 0) ? 0.0f : vp[s];
    obTT[o] = (px == 0) ? 0.0f : Tp[s];
    if (y < 0 || y >= NY || x < 0 || x >= NX) return;
    float ru[3][3], rv[3][3], rt[3][3];
    g9(up, y, x, 1.5f, ru);
    g9(vp, y, x, 0.0f, rv);
    g9(Tp, y, x, 0.0f, rt);
    float uav = ru[1][1], vav = rv[1][1];   // advecting velocity = predictor
    float sig = sigma_at(y, x);
    size_t i = (size_t)y * NX + x;
    float un = u[i] + DT * (uav * cxv(ru) + vav * cyv(ru) + NU * cdv(ru));
    float vn = v[i] + DT * (uav * cxv(rv) + vav * cyv(rv) + NU * cdv(rv));
    float Tn = T[i] + DT * (uav * cxv(rt) + vav * cyv(rt) + AT * cdv(rt));
    float den = 1.0f + DT * sig;
    un /= den; vn /= den;
    if (sig > 0.0f) Tn = 1.0f;
    us[i] = un; vs[i] = vn; oT[i] = Tn;
}

// K3: pressure Poisson rhs (+ writes uu_star/vv_star pads).
__global__ void rhsdiv_k(const float* __restrict__ us, const float* __restrict__ vs,
                         float* __restrict__ rhs,
                         float* __restrict__ ouus, float* __restrict__ ovvs) {
    int px = blockIdx.x * blockDim.x + threadIdx.x;
    int py = blockIdx.y;
    if (px >= PX) return;
    int y = py - 1, x = px - 1;
    int cy = min(max(y, 0), NY - 1), cx = min(max(x, 0), NX - 1);
    size_t o = (size_t)py * PX + px, s = (size_t)cy * NX + cx;
    ouus[o] = (px == 0) ? 1.5f : us[s];
    ovvs[o] = (px == 0) ? 0.0f : vs[s];
    if (y < 0 || y >= NY || x < 0 || x >= NX) return;
    float ru[3][3], rv[3][3];
    g9(us, y, x, 1.5f, ru);
    g9(vs, y, x, 0.0f, rv);
    rhs[(size_t)y * NX + x] = (cxv(ru) + cyv(rv)) * (1.0f / DT);
}

// K4-K8: 2D-tiled fused Jacobi, JK iterations per launch.
// Tile = core CHxCW + halo 8 all around, ping-pong in LDS.
__global__ __launch_bounds__(256)
void jacobi2d(const float* __restrict__ pin, const float* __restrict__ rhs,
              float* __restrict__ pout, float* __restrict__ res) {
    __shared__ float pl[2][TH][TLW];   // 23.0 KB
    __shared__ float rl[TH][TLW];      // 11.5 KB
    const int bx = blockIdx.x, by = blockIdx.y;
    const int tid = threadIdx.x;
    const int gx0 = bx * CW - HALO, gy0 = by * CH - HALO;

    // Load tile with bc_p folded: rows edge-clamped, left edge-clamped,
    // east-of-domain = 0 (outlet pad). Zeros persist in BOTH buffers.
    for (int i = tid; i < TH * TLW; i += 256) {
        int ly = i / TLW, lx = i - ly * TLW;
        float pv = 0.0f, rv = 0.0f;
        int gx = gx0 + lx;
        if (lx < TW && gx < NX) {
            int cy = min(max(gy0 + ly, 0), NY - 1);
            int cx = max(gx, 0);
            size_t s = (size_t)cy * NX + cx;
            pv = pin[s];
            rv = rhs[s];
        }
        pl[0][ly][lx] = pv;
        pl[1][ly][lx] = pv;
        rl[ly][lx] = rv;
    }
    __syncthreads();

    const int q  = tid & 15;          // column quad (0..13 active)
    const int g  = tid >> 4;          // row group (0..15)
    const int lx0 = q * 4;
    // last column block: cols >= CW+HALO are outlet zeros, never update them
    const bool compute = (q < 14) && !((bx == BXN - 1) && (lx0 >= CW + HALO));
    const int r0 = 1 + 3 * g;
    const int r1 = min(r0 + 2, TH - 2);
    const bool wbc = (bx == 0) && (lx0 == HALO);      // cell gx==0: west = self
    const bool top = (by == 0), bot = (by == BYN - 1);
    const int lm = max(lx0 - 2, 0);
    const int lp = min(lx0 + 4, TW - 2);
    const bool wres = (res != nullptr);

    int cb = 0;
    for (int j = 0; j < JK; ++j) {
        const bool last = (j == JK - 1);
        if (compute) {
            float (*cur)[TLW] = pl[cb];
            float (*nxt)[TLW] = pl[cb ^ 1];
            float aL, aR, bL, bR, cL, cR;
            float4 aC, bC, cC;
            auto ld = [&](int rr, float& L, float4& C, float& R) {
                const float* row = &cur[rr][0];
                float2 lo = *(const float2*)(row + lm);
                C = *(const float4*)(row + lx0);
                float2 hi = *(const float2*)(row + lp);
                L = wbc ? C.x : lo.y;
                R = hi.x;
            };
            ld(r0 - 1, aL, aC, aR);
            ld(r0,     bL, bC, bR);
            for (int r = r0; r <= r1; ++r) {
                ld(r + 1, cL, cC, cR);
                bool nbc = top && (r == HALO);           // gy==0: north = self
                bool sbc = bot && (r == HALO + CH - 1);  // gy==NY-1: south = self
                float  nL = nbc ? bL : aL, nR = nbc ? bR : aR;
                float4 nC = nbc ? bC : aC;
                float  sL = sbc ? bL : cL, sR = sbc ? bR : cR;
                float4 sC = sbc ? bC : cC;
                float4 rq = *(const float4*)(&rl[r][lx0]);
                float s0 = nL   + nC.x + nC.y + bL   + bC.y + sL   + sC.x + sC.y;
                float s1 = nC.x + nC.y + nC.z + bC.x + bC.z + sC.x + sC.y + sC.z;
                float s2 = nC.y + nC.z + nC.w + bC.y + bC.w + sC.y + sC.z + sC.w;
                float s3 = nC.z + nC.w + nR   + bC.z + bR   + sC.z + sC.w + sR;
                float e0 = (8.0f * bC.x - s0) * (1.0f / 3.0f) - rq.x;
                float e1 = (8.0f * bC.y - s1) * (1.0f / 3.0f) - rq.y;
                float e2 = (8.0f * bC.z - s2) * (1.0f / 3.0f) - rq.z;
                float e3 = (8.0f * bC.w - s3) * (1.0f / 3.0f) - rq.w;
                float4 pn = { bC.x - 0.375f * e0, bC.y - 0.375f * e1,
                              bC.z - 0.375f * e2, bC.w - 0.375f * e3 };
                *(float4*)(&nxt[r][lx0]) = pn;
                if (last && wres) {          // residual of final iteration;
                    float4 e4 = { e0, e1, e2, e3 };   // rhs read pointwise by
                    *(float4*)(&rl[r][lx0]) = e4;     // owner only -> safe
                }
                aL = bL; aC = bC; aR = bR;
                bL = cL; bC = cC; bR = cR;
            }
        }
        cb ^= 1;
        __syncthreads();
    }

    // Write core region (final state is in pl[0] after an even iter count).
    for (int i = tid; i < CH * CW; i += 256) {
        int y = i / CW, x = i - y * CW;
        size_t o = (size_t)(by * CH + y) * NX + (bx * CW + x);
        pout[o] = pl[0][y + HALO][x + HALO];
        if (wres) res[o] = rl[y + HALO][x + HALO];
    }
}

// K9: projection (+ writes o_pp = bc_p(p)).
__global__ void proj2_k(const float* __restrict__ us, const float* __restrict__ vs,
                        const float* __restrict__ p,
                        float* __restrict__ un, float* __restrict__ vn,
                        float* __restrict__ opp) {
    int px = blockIdx.x * blockDim.x + threadIdx.x;
    int py = blockIdx.y;
    if (px >= PX) return;
    int y = py - 1, x = px - 1;
    int cy = min(max(y, 0), NY - 1);
    opp[(size_t)py * PX + px] =
        (px == PX - 1) ? 0.0f : p[(size_t)cy * NX + max(x, 0)];
    if (y < 0 || y >= NY || x < 0 || x >= NX) return;
    float rp[3][3];
    g9p(p, y, x, rp);
    float sig = sigma_at(y, x);
    float den = 1.0f + DT * sig;
    size_t i = (size_t)y * NX + x;
    un[i] = (us[i] + cxv(rp) * DT) / den;
    vn[i] = (vs[i] + cyv(rp) * DT) / den;
}

extern "C" void kernel_launch(void* const* d_in, const int* in_sizes, int n_in,
                              void* d_out, int out_size, void* d_ws, size_t ws_size,
                              hipStream_t stream) {
    const float* u = (const float*)d_in[0];
    const float* v = (const float*)d_in[1];
    const float* p = (const float*)d_in[2];
    const float* T = (const float*)d_in[3];

    float* out = (float*)d_out;
    float* o_u   = out;
    float* o_v   = out + (size_t)NI;
    float* o_p   = out + 2 * (size_t)NI;
    float* o_T   = out + 3 * (size_t)NI;
    float* o_uus = out + 4 * (size_t)NI;
    float* o_vvs = o_uus + (size_t)NP;
    float* o_pp  = o_uus + 2 * (size_t)NP;
    float* o_TT  = o_uus + 3 * (size_t)NP;
    float* o_buu = o_uus + 4 * (size_t)NP;
    float* o_bvv = o_uus + 5 * (size_t)NP;
    float* o_bTT = o_uus + 6 * (size_t)NP;
    float* o_res = o_uus + 7 * (size_t)NP;

    // ws slots (5 x NI floats = 21.1 MB):
    //   w0: u_pred -> jacobi ping A    w1: v_pred -> jacobi ping B
    //   w2: T_pred -> rhs              w3: u_star  w4: v_star
    float* w  = (float*)d_ws;
    float* s_up  = w;
    float* s_vp  = w + (size_t)NI;
    float* s_Tp  = w + 2 * (size_t)NI;
    float* s_us  = w + 3 * (size_t)NI;
    float* s_vs  = w + 4 * (size_t)NI;
    float* s_rhs = s_Tp;
    float* pA = s_up;
    float* pB = s_vp;

    dim3 blk(256, 1, 1);
    dim3 gp((PX + 255) / 256, PY, 1);
    dim3 gj(BXN, BYN, 1);

    pred_k<<<gp, blk, 0, stream>>>(u, v, T, s_up, s_vp, s_Tp, o_TT);
    corr_k<<<gp, blk, 0, stream>>>(u, v, T, s_up, s_vp, s_Tp,
                                   s_us, s_vs, o_T, o_buu, o_bvv, o_bTT);
    rhsdiv_k<<<gp, blk, 0, stream>>>(s_us, s_vs, s_rhs, o_uus, o_vvs);

    // 40 Jacobi iterations = 5 fused launches x 8
    jacobi2d<<<gj, blk, 0, stream>>>(p,  s_rhs, pA,  nullptr);
    jacobi2d<<<gj, blk, 0, stream>>>(pA, s_rhs, pB,  nullptr);
    jacobi2d<<<gj, blk, 0, stream>>>(pB, s_rhs, pA,  nullptr);
    jacobi2d<<<gj, blk, 0, stream>>>(pA, s_rhs, pB,  nullptr);
    jacobi2d<<<gj, blk, 0, stream>>>(pB, s_rhs, o_p, o_res);

    proj2_k<<<gp, blk, 0, stream>>>(s_us, s_vs, o_p, o_u, o_v, o_pp);
}

// Round 7
// 153.681 us; speedup vs baseline: 2.2083x; 1.0388x over previous
//
#include <hip/hip_runtime.h>

// One timestep of the AI4CFD semicircle-cylinder NS solver.
// Grid: interior NY x NX = 160 x 6600, padded PY x PX = 162 x 6602.
// Round 7 (bisect): round-3 PROVEN jacobi stencil body (LDS neighbor reads,
// scalar clamped loader, NO DPP) + two DPP-free optimizations only:
//   (a) rhs in registers (rl LDS tile dropped: 34.5 -> 23.0 KB/block)
//   (b) final iteration stores core cells directly to global from registers.
// 5 stream-ordered jacobi launches; aux kernels unchanged (proven r1-3).

namespace {
constexpr int NY = 160, NX = 6600, PY = 162, PX = 6602;
constexpr int NI = NY * NX;   // 1,056,000
constexpr int NP = PY * PX;   // 1,069,524
constexpr float DT  = 0.005f;
constexpr float NU  = 0.01f;          // 1/RE
constexpr float AT  = 1.0f / 70.0f;   // 1/(RE*PR)

constexpr int JK   = 8;               // iterations per stage
constexpr int HALO = 8;
constexpr int CW   = 40, CH = 32;     // core tile
constexpr int TW   = CW + 2 * HALO;   // 56
constexpr int TH   = CH + 2 * HALO;   // 48
constexpr int TLW  = 60;              // LDS row stride (floats), round-3 proven
constexpr int BXN  = NX / CW;         // 165
constexpr int BYN  = NY / CH;         // 5
}

// Brinkman penalization field: semicircle at (x=1800, y=80), R=20, x>=1800.
__device__ __forceinline__ float sigma_at(int y, int x) {
    int ddx = x - 1800, ddy = y - 80;
    return ((ddx * ddx + ddy * ddy <= 400) && (x >= 1800)) ? 1.0e6f : 0.0f;
}

// ---- stencil weights ----
__device__ __forceinline__ float cxv(const float r[3][3]) {   // w_xadv
    return (r[0][0] - r[0][2] + 4.0f * (r[1][0] - r[1][2]) + r[2][0] - r[2][2])
           * (1.0f / 12.0f);
}
__device__ __forceinline__ float cyv(const float r[3][3]) {   // w_yadv
    return (r[0][0] + 4.0f * r[0][1] + r[0][2]
            - r[2][0] - 4.0f * r[2][1] - r[2][2]) * (1.0f / 12.0f);
}
__device__ __forceinline__ float cdv(const float r[3][3]) {   // w_diff
    return (r[0][0] + r[0][1] + r[0][2]
            + r[1][0] - 8.0f * r[1][1] + r[1][2]
            + r[2][0] + r[2][1] + r[2][2]) * (1.0f / 3.0f);
}

// g9 / g9p gathers for the aux kernels.
__device__ __forceinline__ void g9(const float* __restrict__ a, int y, int x,
                                   float lc, float r[3][3]) {
    int ym = max(y - 1, 0), yp = min(y + 1, NY - 1);
    int xp = min(x + 1, NX - 1);
    const float* r0 = a + (size_t)ym * NX;
    const float* r1 = a + (size_t)y  * NX;
    const float* r2 = a + (size_t)yp * NX;
    if (x == 0) { r[0][0] = lc; r[1][0] = lc; r[2][0] = lc; }
    else        { r[0][0] = r0[x-1]; r[1][0] = r1[x-1]; r[2][0] = r2[x-1]; }
    r[0][1] = r0[x]; r[0][2] = r0[xp];
    r[1][1] = r1[x]; r[1][2] = r1[xp];
    r[2][1] = r2[x]; r[2][2] = r2[xp];
}
__device__ __forceinline__ void g9p(const float* __restrict__ a, int y, int x,
                                    float r[3][3]) {
    int ym = max(y - 1, 0), yp = min(y + 1, NY - 1);
    int xm = max(x - 1, 0);
    bool rb = (x == NX - 1);
    const float* r0 = a + (size_t)ym * NX;
    const float* r1 = a + (size_t)y  * NX;
    const float* r2 = a + (size_t)yp * NX;
    r[0][0] = r0[xm]; r[0][1] = r0[x]; r[0][2] = rb ? 0.0f : r0[x+1];
    r[1][0] = r1[xm]; r[1][1] = r1[x]; r[1][2] = rb ? 0.0f : r1[x+1];
    r[2][0] = r2[xm]; r[2][1] = r2[x]; r[2][2] = rb ? 0.0f : r2[x+1];
}

// ---------------- aux kernels (unchanged, proven in rounds 1-3) ----------------
__global__ void pred_k(const float* __restrict__ u, const float* __restrict__ v,
                       const float* __restrict__ T,
                       float* __restrict__ up, float* __restrict__ vp,
                       float* __restrict__ Tp, float* __restrict__ oTT) {
    int px = blockIdx.x * blockDim.x + threadIdx.x;
    int py = blockIdx.y;
    if (px >= PX) return;
    int y = py - 1, x = px - 1;
    int cy = min(max(y, 0), NY - 1), cx = min(max(x, 0), NX - 1);
    oTT[(size_t)py * PX + px] = (px == 0) ? 0.0f : T[(size_t)cy * NX + cx];
    if (y < 0 || y >= NY || x < 0 || x >= NX) return;
    float ru[3][3], rv[3][3], rt[3][3];
    g9(u, y, x, 1.5f, ru);
    g9(v, y, x, 0.0f, rv);
    g9(T, y, x, 0.0f, rt);
    float uav = ru[1][1], vav = rv[1][1];
    float sig = sigma_at(y, x);
    const float hdt = 0.5f * DT;
    float un = ru[1][1] + hdt * (uav * cxv(ru) + vav * cyv(ru) + NU * cdv(ru));
    float vn = rv[1][1] + hdt * (uav * cxv(rv) + vav * cyv(rv) + NU * cdv(rv));
    float Tn = rt[1][1] + hdt * (uav * cxv(rt) + vav * cyv(rt) + AT * cdv(rt));
    float den = 1.0f + hdt * sig;
    un /= den; vn /= den;
    if (sig > 0.0f) Tn = 1.0f;
    size_t i = (size_t)y * NX + x;
    up[i] = un; vp[i] = vn; Tp[i] = Tn;
}

__global__ void corr_k(const float* __restrict__ u, const float* __restrict__ v,
                       const float* __restrict__ T,
                       const float* __restrict__ up, const float* __restrict__ vp,
                       const float* __restrict__ Tp,
                       float* __restrict__ us, float* __restrict__ vs,
                       float* __restrict__ oT,
                       float* __restrict__ obuu, float* __restrict__ obvv,
                       float* __restrict__ obTT) {
    int px = blockIdx.x * blockDim.x + threadIdx.x;
    int py = blockIdx.y;
    if (px >= PX) return;
    int y = py - 1, x = px - 1;
    int cy = min(max(y, 0), NY - 1), cx = min(max(x, 0), NX - 1);
    size_t o = (size_t)py * PX + px, s = (size_t)cy * NX + cx;
    obuu[o] = (px == 0) ? 1.5f : up[s];
    obvv[o] = (px == 0) ? 0.0f : vp[s];
    obTT[o] = (px == 0) ? 0.0f : Tp[s];
    if (y < 0 || y >= NY || x < 0 || x >= NX) return;
    float ru[3][3], rv[3][3], rt[3][3];
    g9(up, y, x, 1.5f, ru);
    g9(vp, y, x, 0.0f, rv);
    g9(Tp, y, x, 0.0f, rt);
    float uav = ru[1][1], vav = rv[1][1];
    float sig = sigma_at(y, x);
    size_t i = (size_t)y * NX + x;
    float un = u[i] + DT * (uav * cxv(ru) + vav * cyv(ru) + NU * cdv(ru));
    float vn = v[i] + DT * (uav * cxv(rv) + vav * cyv(rv) + NU * cdv(rv));
    float Tn = T[i] + DT * (uav * cxv(rt) + vav * cyv(rt) + AT * cdv(rt));
    float den = 1.0f + DT * sig;
    un /= den; vn /= den;
    if (sig > 0.0f) Tn = 1.0f;
    us[i] = un; vs[i] = vn; oT[i] = Tn;
}

__global__ void rhsdiv_k(const float* __restrict__ us, const float* __restrict__ vs,
                         float* __restrict__ rhs,
                         float* __restrict__ ouus, float* __restrict__ ovvs) {
    int px = blockIdx.x * blockDim.x + threadIdx.x;
    int py = blockIdx.y;
    if (px >= PX) return;
    int y = py - 1, x = px - 1;
    int cy = min(max(y, 0), NY - 1), cx = min(max(x, 0), NX - 1);
    size_t o = (size_t)py * PX + px, s = (size_t)cy * NX + cx;
    ouus[o] = (px == 0) ? 1.5f : us[s];
    ovvs[o] = (px == 0) ? 0.0f : vs[s];
    if (y < 0 || y >= NY || x < 0 || x >= NX) return;
    float ru[3][3], rv[3][3];
    g9(us, y, x, 1.5f, ru);
    g9(vs, y, x, 0.0f, rv);
    rhs[(size_t)y * NX + x] = (cxv(ru) + cyv(rv)) * (1.0f / DT);
}

__global__ void proj2_k(const float* __restrict__ us, const float* __restrict__ vs,
                        const float* __restrict__ p,
                        float* __restrict__ un, float* __restrict__ vn,
                        float* __restrict__ opp) {
    int px = blockIdx.x * blockDim.x + threadIdx.x;
    int py = blockIdx.y;
    if (px >= PX) return;
    int y = py - 1, x = px - 1;
    int cy = min(max(y, 0), NY - 1);
    opp[(size_t)py * PX + px] =
        (px == PX - 1) ? 0.0f : p[(size_t)cy * NX + max(x, 0)];
    if (y < 0 || y >= NY || x < 0 || x >= NX) return;
    float rp[3][3];
    g9p(p, y, x, rp);
    float sig = sigma_at(y, x);
    float den = 1.0f + DT * sig;
    size_t i = (size_t)y * NX + x;
    un[i] = (us[i] + cxv(rp) * DT) / den;
    vn[i] = (vs[i] + cyv(rp) * DT) / den;
}

// ---------------- fused Jacobi stage: round-3 body + rhs-regs + direct store ----
__device__ __forceinline__ void load_rhs_regs(const float* __restrict__ rhs,
                                              float4 (&rq)[3]) {
    const int tid = threadIdx.x;
    const int q = tid & 15, g = tid >> 4;
    const int gx0 = blockIdx.x * CW - HALO, gy0 = blockIdx.y * CH - HALO;
    const int r0 = 1 + 3 * g;
#pragma unroll
    for (int k = 0; k < 3; ++k) {
        int r = min(r0 + k, TH - 2);
        int cy = min(max(gy0 + r, 0), NY - 1);
        int cx = min(max(gx0 + 4 * q, 0), NX - 4);
        rq[k] = *(const float4*)(rhs + (size_t)cy * NX + cx);
    }
}

__global__ __launch_bounds__(256)
void jacobi_single(const float* __restrict__ src, const float* __restrict__ rhs,
                   float* __restrict__ dst, float* __restrict__ res) {
    __shared__ float pl[2][TH][TLW];   // 23.0 KB
    float4 rq[3];
    load_rhs_regs(rhs, rq);

    const int bx = blockIdx.x, by = blockIdx.y;
    const int tid = threadIdx.x;
    const int gx0 = bx * CW - HALO, gy0 = by * CH - HALO;

    // round-3 proven loader (scalar, clamped; east-of-domain zeros, both buffers)
    for (int i = tid; i < TH * TLW; i += 256) {
        int ly = i / TLW, lx = i - ly * TLW;
        float pv = 0.0f;
        int gx = gx0 + lx;
        if (lx < TW && gx < NX) {
            int cy = min(max(gy0 + ly, 0), NY - 1);
            pv = src[(size_t)cy * NX + max(gx, 0)];
        }
        pl[0][ly][lx] = pv;
        pl[1][ly][lx] = pv;
    }
    __syncthreads();

    const int q  = tid & 15;          // column quad
    const int g  = tid >> 4;          // row group
    const int lx0 = q * 4;
    const bool compute = (q < 14) && !((bx == BXN - 1) && (lx0 >= CW + HALO));
    const int r0 = 1 + 3 * g;
    const int r1 = min(r0 + 2, TH - 2);
    const bool wbc = (bx == 0) && (lx0 == HALO);      // cell gx==0: west = self
    const bool top = (by == 0), bot = (by == BYN - 1);
    const int lm = max(lx0 - 2, 0);
    const int lp = min(lx0 + 4, TW - 2);
    const bool wres = (res != nullptr);

    int cb = 0;
    for (int j = 0; j < JK; ++j) {
        const bool last_it = (j == JK - 1);
        float (*cur)[TLW] = pl[cb];
        float (*nxt)[TLW] = pl[cb ^ 1];
        float aL, aR, bL, bR, cL, cR;
        float4 aC, bC, cC;
        auto ld = [&](int rr, float& L, float4& C, float& R) {
            const float* row = &cur[rr][0];
            float2 lo = *(const float2*)(row + lm);
            C = *(const float4*)(row + lx0);
            float2 hi = *(const float2*)(row + lp);
            L = wbc ? C.x : lo.y;
            R = hi.x;
        };
        ld(r0 - 1, aL, aC, aR);
        ld(r0,     bL, bC, bR);
        for (int k = 0; k < 3; ++k) {
            const int r = r0 + k;
            if (r <= r1) {
                ld(r + 1, cL, cC, cR);
                bool nbc = top && (r == HALO);           // gy==0: north = self
                bool sbc = bot && (r == HALO + CH - 1);  // gy==NY-1: south = self
                float  nL = nbc ? bL : aL, nR = nbc ? bR : aR;
                float4 nC = nbc ? bC : aC;
                float  sL = sbc ? bL : cL, sR = sbc ? bR : cR;
                float4 sC = sbc ? bC : cC;
                float s0 = nL   + nC.x + nC.y + bL   + bC.y + sL   + sC.x + sC.y;
                float s1 = nC.x + nC.y + nC.z + bC.x + bC.z + sC.x + sC.y + sC.z;
                float s2 = nC.y + nC.z + nC.w + bC.y + bC.w + sC.y + sC.z + sC.w;
                float s3 = nC.z + nC.w + nR   + bC.z + bR   + sC.z + sC.w + sR;
                float e0 = (8.0f * bC.x - s0) * (1.0f / 3.0f) - rq[k].x;
                float e1 = (8.0f * bC.y - s1) * (1.0f / 3.0f) - rq[k].y;
                float e2 = (8.0f * bC.z - s2) * (1.0f / 3.0f) - rq[k].z;
                float e3 = (8.0f * bC.w - s3) * (1.0f / 3.0f) - rq[k].w;
                float4 pn = make_float4(bC.x - 0.375f * e0, bC.y - 0.375f * e1,
                                        bC.z - 0.375f * e2, bC.w - 0.375f * e3);
                if (last_it) {
                    // direct global store of core cells (each exactly once)
                    if (compute && r >= HALO && r < HALO + CH &&
                        lx0 >= HALO && lx0 < HALO + CW) {
                        size_t o = (size_t)(gy0 + r) * NX + (gx0 + lx0);
                        *(float4*)(dst + o) = pn;
                        if (wres) {
                            float4 e4 = make_float4(e0, e1, e2, e3);
                            *(float4*)(res + o) = e4;
                        }
                    }
                } else if (compute) {
                    *(float4*)(&nxt[r][lx0]) = pn;
                }
                aL = bL; aC = bC; aR = bR;
                bL = cL; bC = cC; bR = cR;
            }
        }
        cb ^= 1;
        __syncthreads();
    }
}

extern "C" void kernel_launch(void* const* d_in, const int* in_sizes, int n_in,
                              void* d_out, int out_size, void* d_ws, size_t ws_size,
                              hipStream_t stream) {
    const float* u = (const float*)d_in[0];
    const float* v = (const float*)d_in[1];
    const float* p = (const float*)d_in[2];
    const float* T = (const float*)d_in[3];

    float* out = (float*)d_out;
    float* o_u   = out;
    float* o_v   = out + (size_t)NI;
    float* o_p   = out + 2 * (size_t)NI;
    float* o_T   = out + 3 * (size_t)NI;
    float* o_uus = out + 4 * (size_t)NI;
    float* o_vvs = o_uus + (size_t)NP;
    float* o_pp  = o_uus + 2 * (size_t)NP;
    float* o_TT  = o_uus + 3 * (size_t)NP;
    float* o_buu = o_uus + 4 * (size_t)NP;
    float* o_bvv = o_uus + 5 * (size_t)NP;
    float* o_bTT = o_uus + 6 * (size_t)NP;
    float* o_res = o_uus + 7 * (size_t)NP;

    float* w  = (float*)d_ws;
    float* s_up  = w;                      // u_pred -> jacobi ping A
    float* s_vp  = w + (size_t)NI;         // v_pred -> jacobi ping B
    float* s_Tp  = w + 2 * (size_t)NI;     // T_pred -> rhs
    float* s_us  = w + 3 * (size_t)NI;     // u_star
    float* s_vs  = w + 4 * (size_t)NI;     // v_star
    float* s_rhs = s_Tp;
    float* pA = s_up;
    float* pB = s_vp;

    dim3 blk(256, 1, 1);
    dim3 gp((PX + 255) / 256, PY, 1);
    dim3 gj(BXN, BYN, 1);

    pred_k<<<gp, blk, 0, stream>>>(u, v, T, s_up, s_vp, s_Tp, o_TT);
    corr_k<<<gp, blk, 0, stream>>>(u, v, T, s_up, s_vp, s_Tp,
                                   s_us, s_vs, o_T, o_buu, o_bvv, o_bTT);
    rhsdiv_k<<<gp, blk, 0, stream>>>(s_us, s_vs, s_rhs, o_uus, o_vvs);

    // 40 Jacobi iterations = 5 stream-ordered launches x 8 fused iters
    jacobi_single<<<gj, blk, 0, stream>>>(p,  s_rhs, pA,  nullptr);
    jacobi_single<<<gj, blk, 0, stream>>>(pA, s_rhs, pB,  nullptr);
    jacobi_single<<<gj, blk, 0, stream>>>(pB, s_rhs, pA,  nullptr);
    jacobi_single<<<gj, blk, 0, stream>>>(pA, s_rhs, pB,  nullptr);
    jacobi_single<<<gj, blk, 0, stream>>>(pB, s_rhs, o_p, o_res);

    proj2_k<<<gp, blk, 0, stream>>>(s_us, s_vs, o_p, o_u, o_v, o_pp);
}